// Round 8
// baseline (377.020 us; speedup 1.0000x reference)
//
#include <hip/hip_runtime.h>
#include <stdint.h>

// ---------------------------------------------------------------------------
// WeedLayer. B=8, C=64, H=W=256, PD=32, STRIDE=16 -> n=15, L=225, P=16, E=512,
// HEADS=8, hd=64, fv=4096. X = [patches(128); blocks(1800)] = 1928 rows.
// R8: hist via 64 private LDS copies (stride 69, conflict-free, ~no atomic
//     serialization); pooling 2 outputs/thread for 2x load ILP. 7 dispatches.
// ---------------------------------------------------------------------------

typedef __attribute__((ext_vector_type(8))) short bf16x8;
typedef __attribute__((ext_vector_type(4))) float f32x4;

__device__ __forceinline__ unsigned short f2bf(float x) {
    union { float f; unsigned u; } v; v.f = x;
    unsigned r = v.u + 0x7FFFu + ((v.u >> 16) & 1u);   // RNE
    return (unsigned short)(r >> 16);
}
__device__ __forceinline__ float bf2f(unsigned short x) {
    union { unsigned u; float f; } v; v.u = ((unsigned)x) << 16; return v.f;
}

__device__ __forceinline__ void g2l16(const unsigned short* g, unsigned short* l) {
    __builtin_amdgcn_global_load_lds(
        (const __attribute__((address_space(1))) unsigned int*)g,
        (__attribute__((address_space(3))) unsigned int*)l, 16, 0, 0);
}

// --- K_prep: pool_features | pool_patches | weight f2bf | hist partials -----
// blocks: [0,2048) features  [2048,3072) patches  [3072,6400) weights
//         [6400,6912) hist
__global__ __launch_bounds__(256) void k_prep(
    const float* __restrict__ f, const float* __restrict__ p,
    const float* __restrict__ Wr, const float* __restrict__ Wqkv,
    const float* __restrict__ Wo, const float* __restrict__ Wm,
    const int* __restrict__ masks, const float* __restrict__ probs,
    unsigned short* __restrict__ gp, unsigned short* __restrict__ Xb,
    unsigned short* __restrict__ oWr, unsigned short* __restrict__ oWqkv,
    unsigned short* __restrict__ oWo, unsigned short* __restrict__ oWm,
    float* __restrict__ hpart)
{
    int blk = blockIdx.x, tid = threadIdx.x;
    if (blk < 2048) {
        // feature pool: 2 output rows per thread (16 outstanding float4 loads)
        unsigned t = blk * 256u + tid;                   // 524,288 units
        unsigned q2 = t & 63u, rh = (t >> 6) & 63u, g = (t >> 12) & 15u, b = t >> 16;
        const float4* f4 = (const float4*)f;
        unsigned cb = b * 64u + g * 4u;
        float s[2][2] = {{0.f, 0.f}, {0.f, 0.f}};
#pragma unroll
        for (int rr = 0; rr < 2; ++rr) {
            unsigned r = rh + rr * 64u;
#pragma unroll
            for (int j = 0; j < 4; ++j)
#pragma unroll
                for (int a = 0; a < 2; ++a) {
                    float4 v = f4[((cb + j) * 256u + 2u * r + a) * 64u + q2];
                    s[rr][0] += v.x + v.y; s[rr][1] += v.z + v.w;
                }
        }
#pragma unroll
        for (int rr = 0; rr < 2; ++rr) {
            unsigned r = rh + rr * 64u;
            ushort2 o; o.x = f2bf(s[rr][0] * 0.0625f); o.y = f2bf(s[rr][1] * 0.0625f);
            ((ushort2*)gp)[((b * 16u + g) * 128u + r) * 64u + q2] = o;
        }
    } else if (blk < 3072) {
        // patch pool: 2 outputs per thread via float4 loads
        unsigned t = (blk - 2048) * 256u + tid;          // 262,144 units
        unsigned q4 = t & 7u, r = (t >> 3) & 15u, g = (t >> 7) & 15u, row = t >> 11;
        const float4* p4 = (const float4*)p;
        float s0 = 0.f, s1 = 0.f;
        unsigned cb = row * 64u + g * 4u;
#pragma unroll
        for (int j = 0; j < 4; ++j)
#pragma unroll
            for (int a = 0; a < 2; ++a) {
                float4 v = p4[((cb + j) * 32u + 2u * r + a) * 8u + q4];
                s0 += v.x + v.y; s1 += v.z + v.w;
            }
        ushort2 o; o.x = f2bf(s0 * 0.0625f); o.y = f2bf(s1 * 0.0625f);
        *(ushort2*)(Xb + (size_t)row * 4096 + g * 256 + r * 16 + 2 * q4) = o;
    } else if (blk < 6400) {
        int t = (blk - 3072) * 256 + tid;                // 851,968 float4 groups
        const float* src; unsigned short* dst; int i;
        if (t < 524288)      { src = Wr;   dst = oWr;   i = t; }
        else if (t < 720896) { src = Wqkv; dst = oWqkv; i = t - 524288; }
        else if (t < 786432) { src = Wo;   dst = oWo;   i = t - 720896; }
        else                 { src = Wm;   dst = oWm;   i = t - 786432; }
        float4 v = ((const float4*)src)[i];
        ushort4 o;
        o.x = f2bf(v.x); o.y = f2bf(v.y); o.z = f2bf(v.z); o.w = f2bf(v.w);
        ((ushort4*)dst)[i] = o;
    } else {
        // hist: 64 private copies (one per lane id), stride 69 -> conflict-free;
        // atomics only serialize across the 4 waves sharing a lane id.
        __shared__ float ls[64 * 69];                    // 17.7 KB
        int hb = blk - 6400;
        int b = hb >> 6, chunk = hb & 63;
        int lane = tid & 63;
        float* my = &ls[lane * 69];
        for (int i = tid; i < 64 * 69; i += 256) ls[i] = 0.f;
        __syncthreads();
        int base = chunk * 1024;
        for (int it = 0; it < 4; ++it) {
            int px = base + it * 256 + tid;
            int lab = masks[b * 65536 + px];
            atomicAdd(&my[lab * 3 + 0], probs[(size_t)(b * 3 + 0) * 65536 + px]);
            atomicAdd(&my[lab * 3 + 1], probs[(size_t)(b * 3 + 1) * 65536 + px]);
            atomicAdd(&my[lab * 3 + 2], probs[(size_t)(b * 3 + 2) * 65536 + px]);
            atomicAdd(&my[51 + lab], 1.f);
        }
        __syncthreads();
        if (tid < 68) {
            float s = 0.f;
            for (int c = 0; c < 64; ++c) s += ls[c * 69 + tid];
            hpart[(size_t)hb * 68 + tid] = s;
        }
    }
}

// --- 128x128-tile bf16 NT GEMM; GATHER reads block rows from Gp -------------
template<bool GATHER>
__global__ __launch_bounds__(256) void k_gemm128(
    const unsigned short* __restrict__ A, const unsigned short* __restrict__ Gp,
    const unsigned short* __restrict__ Bw,
    float* __restrict__ C, int M, int N, int K, int klen)
{
    __shared__ __align__(16) unsigned short As[128 * 32];
    __shared__ __align__(16) unsigned short Bs[128 * 32];
    const int tid = threadIdx.x, w = tid >> 6, lane = tid & 63;
    const int nt = blockIdx.x, mt = blockIdx.y, ks = blockIdx.z;
    const int kbase = ks * klen;
    const int l15 = lane & 15, kq = (lane >> 4) * 8;
    const int wm = (w >> 1) * 64, wn = (w & 1) * 64;
    const int srow0 = w * 32, lrow = lane >> 2, lcol = (lane & 3) * 8;

    size_t arowbase[2]; bool apatch[2];
#pragma unroll
    for (int c = 0; c < 2; ++c) {
        int r = srow0 + c * 16 + lrow;
        int ga = mt * 128 + r; if (ga > M - 1) ga = M - 1;
        if (GATHER && ga >= 128) {
            int rr = ga - 128;
            int bb = rr / 225, ij = rr - bb * 225;
            int ii = ij / 15, jj = ij - ii * 15;
            arowbase[c] = (size_t)bb * 262144 + ii * 1024 + jj * 8;
            apatch[c] = false;
        } else {
            arowbase[c] = (size_t)ga * K;
            apatch[c] = true;
        }
    }
    const int brow0 = nt * 128;

    f32x4 acc[4][4];
#pragma unroll
    for (int i = 0; i < 4; ++i)
#pragma unroll
        for (int j = 0; j < 4; ++j) acc[i][j] = (f32x4){0.f, 0.f, 0.f, 0.f};

    for (int k0 = 0; k0 < klen; k0 += 32) {
        int kcol = kbase + k0 + lcol;
#pragma unroll
        for (int c = 0; c < 2; ++c) {
            const unsigned short* gp_a;
            if (!GATHER || apatch[c]) {
                gp_a = A + arowbase[c] + kcol;
            } else {
                gp_a = Gp + arowbase[c] + ((size_t)(kcol >> 8) << 14)
                     + (((kcol >> 4) & 15) << 7) + (kcol & 15);
            }
            g2l16(gp_a, &As[(srow0 + c * 16) * 32]);
            g2l16(Bw + (size_t)(brow0 + srow0 + c * 16 + lrow) * K + kcol,
                  &Bs[(srow0 + c * 16) * 32]);
        }
        __syncthreads();
        bf16x8 af[4], bf[4];
#pragma unroll
        for (int i = 0; i < 4; ++i) {
            af[i] = *(const bf16x8*)&As[(wm + 16 * i + l15) * 32 + kq];
            bf[i] = *(const bf16x8*)&Bs[(wn + 16 * i + l15) * 32 + kq];
        }
#pragma unroll
        for (int i = 0; i < 4; ++i)
#pragma unroll
            for (int j = 0; j < 4; ++j)
                acc[i][j] = __builtin_amdgcn_mfma_f32_16x16x32_bf16(af[i], bf[j], acc[i][j], 0, 0, 0);
        __syncthreads();
    }
    float* Cp = C + (size_t)ks * M * N;
#pragma unroll
    for (int i = 0; i < 4; ++i) {
        int rowb = mt * 128 + wm + i * 16 + (lane >> 4) * 4;
#pragma unroll
        for (int j = 0; j < 4; ++j) {
            int col = nt * 128 + wn + j * 16 + l15;
#pragma unroll
            for (int r = 0; r < 4; ++r) {
                int row = rowb + r;
                if (row < M) Cp[(size_t)row * N + col] = acc[i][j][r];
            }
        }
    }
}

// --- 64x64-tile bf16 NT GEMM, bias, bf16 out (QKV: high occupancy) ----------
__global__ __launch_bounds__(256) void k_gemm64(
    const unsigned short* __restrict__ A, const unsigned short* __restrict__ Bw,
    const float* __restrict__ bias, unsigned short* __restrict__ Cb,
    int M, int N, int K)
{
    __shared__ __align__(16) unsigned short As[64 * 32];
    __shared__ __align__(16) unsigned short Bs[64 * 32];
    const int tid = threadIdx.x, w = tid >> 6, lane = tid & 63;
    const int bm = blockIdx.y, bn = blockIdx.x;
    const int wm = (w >> 1) * 32, wn = (w & 1) * 32;
    const int l15 = lane & 15, kq = (lane >> 4) * 8;
    const int lrow = lane >> 2, lcol = (lane & 3) * 8;
    int ga = bm * 64 + w * 16 + lrow; if (ga > M - 1) ga = M - 1;
    const unsigned short* Ap = A + (size_t)ga * K;
    const unsigned short* Bp = Bw + (size_t)(bn * 64 + w * 16 + lrow) * K;

    f32x4 acc[2][2];
#pragma unroll
    for (int i = 0; i < 2; ++i)
#pragma unroll
        for (int j = 0; j < 2; ++j) acc[i][j] = (f32x4){0.f, 0.f, 0.f, 0.f};

    for (int k0 = 0; k0 < K; k0 += 32) {
        g2l16(Ap + k0 + lcol, &As[(w * 16) * 32]);
        g2l16(Bp + k0 + lcol, &Bs[(w * 16) * 32]);
        __syncthreads();
        bf16x8 a0 = *(const bf16x8*)&As[(wm + l15) * 32 + kq];
        bf16x8 a1 = *(const bf16x8*)&As[(wm + 16 + l15) * 32 + kq];
        bf16x8 b0 = *(const bf16x8*)&Bs[(wn + l15) * 32 + kq];
        bf16x8 b1 = *(const bf16x8*)&Bs[(wn + 16 + l15) * 32 + kq];
        acc[0][0] = __builtin_amdgcn_mfma_f32_16x16x32_bf16(a0, b0, acc[0][0], 0, 0, 0);
        acc[0][1] = __builtin_amdgcn_mfma_f32_16x16x32_bf16(a0, b1, acc[0][1], 0, 0, 0);
        acc[1][0] = __builtin_amdgcn_mfma_f32_16x16x32_bf16(a1, b0, acc[1][0], 0, 0, 0);
        acc[1][1] = __builtin_amdgcn_mfma_f32_16x16x32_bf16(a1, b1, acc[1][1], 0, 0, 0);
        __syncthreads();
    }
#pragma unroll
    for (int it = 0; it < 2; ++it) {
        int rowb = bm * 64 + wm + it * 16 + (lane >> 4) * 4;
#pragma unroll
        for (int iu = 0; iu < 2; ++iu) {
            int col = bn * 64 + wn + iu * 16 + l15;
            float bv = bias[col];
#pragma unroll
            for (int r = 0; r < 4; ++r) {
                int row = rowb + r;
                if (row < M) Cb[(size_t)row * N + col] = f2bf(acc[it][iu][r] + bv);
            }
        }
    }
}

// --- nsplit-partial reduce + bias + LayerNorm (wave/row) --------------------
__global__ __launch_bounds__(256) void k_lnred(
    const float* __restrict__ Yp, const float* __restrict__ br,
    const float* __restrict__ gg, const float* __restrict__ bb,
    float* __restrict__ outF, unsigned short* __restrict__ outB,
    int rows, int nsplit)
{
    int wave = threadIdx.x >> 6, lane = threadIdx.x & 63;
    int row = blockIdx.x * 4 + wave;
    if (row >= rows) return;
    size_t base = (size_t)row * 512 + lane * 8;
    float v[8];
    { const float* bp = br + lane * 8;
      float4 a = *(const float4*)bp, b = *(const float4*)(bp + 4);
      v[0]=a.x; v[1]=a.y; v[2]=a.z; v[3]=a.w; v[4]=b.x; v[5]=b.y; v[6]=b.z; v[7]=b.w; }
    for (int s = 0; s < nsplit; ++s) {
        const float* xp = Yp + (size_t)s * rows * 512 + base;
        float4 a = *(const float4*)xp, b = *(const float4*)(xp + 4);
        v[0]+=a.x; v[1]+=a.y; v[2]+=a.z; v[3]+=a.w; v[4]+=b.x; v[5]+=b.y; v[6]+=b.z; v[7]+=b.w;
    }
    float s = 0.f;
#pragma unroll
    for (int i = 0; i < 8; ++i) s += v[i];
#pragma unroll
    for (int m = 32; m; m >>= 1) s += __shfl_xor(s, m, 64);
    float mu = s * (1.f / 512.f);
    float sq = 0.f;
#pragma unroll
    for (int i = 0; i < 8; ++i) { float d = v[i] - mu; sq += d * d; }
#pragma unroll
    for (int m = 32; m; m >>= 1) sq += __shfl_xor(sq, m, 64);
    float rstd = rsqrtf(sq * (1.f / 512.f) + 1e-5f);
    const float* gp = gg + lane * 8;
    const float* bp2 = bb + lane * 8;
    float4 g0 = *(const float4*)gp, g1 = *(const float4*)(gp + 4);
    float4 b0 = *(const float4*)bp2, b1 = *(const float4*)(bp2 + 4);
    float ga[8] = {g0.x,g0.y,g0.z,g0.w,g1.x,g1.y,g1.z,g1.w};
    float ba[8] = {b0.x,b0.y,b0.z,b0.w,b1.x,b1.y,b1.z,b1.w};
    float o[8];
#pragma unroll
    for (int i = 0; i < 8; ++i) o[i] = (v[i] - mu) * rstd * ga[i] + ba[i];
    if (row < 128) {
        float* ofp = outF + base;
        float4 w0; w0.x=o[0]; w0.y=o[1]; w0.z=o[2]; w0.w=o[3];
        float4 w1; w1.x=o[4]; w1.y=o[5]; w1.z=o[6]; w1.w=o[7];
        *(float4*)ofp = w0; *(float4*)(ofp + 4) = w1;
    }
    unsigned short* obp = outB + base;
    ushort4 u0, u1;
    u0.x=f2bf(o[0]); u0.y=f2bf(o[1]); u0.z=f2bf(o[2]); u0.w=f2bf(o[3]);
    u1.x=f2bf(o[4]); u1.y=f2bf(o[5]); u1.z=f2bf(o[6]); u1.w=f2bf(o[7]);
    ((ushort4*)obp)[0] = u0; ((ushort4*)obp)[1] = u1;
}

// --- attention: grid (8b, 8h, 4pz); QKV bf16 [1928 x 1536] ------------------
__global__ __launch_bounds__(256) void k_attn(
    const unsigned short* __restrict__ QKVb, unsigned short* __restrict__ attn_bf)
{
    const int b = blockIdx.x, h = blockIdx.y, pz = blockIdx.z;
    __shared__ __align__(16) float qs[4 * 64];
    __shared__ __align__(16) unsigned short Ks[225 * 68];
    __shared__ __align__(16) unsigned short Vs[225 * 64];
    __shared__ float sc[4 * 225];
    const int t = threadIdx.x;

    {
        int p = t >> 6, d = t & 63;
        qs[t] = bf2f(QKVb[(size_t)(b * 16 + pz * 4 + p) * 1536 + h * 64 + d]);
    }
    for (int i = t; i < 1800; i += 256) {
        int l = i >> 3, d8 = (i & 7) * 8;
        size_t base = (size_t)(128 + b * 225 + l) * 1536 + h * 64 + d8;
        uint4 kk4 = *(const uint4*)(QKVb + base + 512);
        *(uint2*)&Ks[l * 68 + d8]     = make_uint2(kk4.x, kk4.y);
        *(uint2*)&Ks[l * 68 + d8 + 4] = make_uint2(kk4.z, kk4.w);
        *(uint4*)&Vs[l * 64 + d8] = *(const uint4*)(QKVb + base + 1024);
    }
    __syncthreads();
    for (int i = t; i < 900; i += 256) {
        int p = i / 225, l = i - p * 225;
        const ushort4* k4 = (const ushort4*)&Ks[l * 68];
        const float4* q4 = (const float4*)&qs[p * 64];
        float s = 0.f;
#pragma unroll
        for (int d = 0; d < 16; ++d) {
            ushort4 kk = k4[d]; float4 qq = q4[d];
            s += bf2f(kk.x) * qq.x + bf2f(kk.y) * qq.y
               + bf2f(kk.z) * qq.z + bf2f(kk.w) * qq.w;
        }
        sc[p * 225 + l] = s * 0.125f;
    }
    __syncthreads();
    const int lane = t & 63, wave = t >> 6;
    {
        float* row = &sc[wave * 225];
        float m = -1e30f;
        for (int l = lane; l < 225; l += 64) m = fmaxf(m, row[l]);
#pragma unroll
        for (int off = 32; off; off >>= 1) m = fmaxf(m, __shfl_xor(m, off, 64));
        float s = 0.f;
        for (int l = lane; l < 225; l += 64) { float e = __expf(row[l] - m); row[l] = e; s += e; }
#pragma unroll
        for (int off = 32; off; off >>= 1) s += __shfl_xor(s, off, 64);
        float inv = 1.f / s;
        for (int l = lane; l < 225; l += 64) row[l] *= inv;
    }
    __syncthreads();
    {
        float o = 0.f;
        const float* scp = &sc[wave * 225];
        for (int l = 0; l < 225; ++l) o += scp[l] * bf2f(Vs[l * 64 + lane]);
        attn_bf[(size_t)(b * 16 + pz * 4 + wave) * 512 + h * 64 + lane] = f2bf(o);
    }
}

// --- tail: Zo=attnb@Wo^T+bo; res=LN(Zo+pe); M1=res@Wm^T+bm;
//     outs=(gelu(M1)+res)@Wc^T+bc.  8 blocks x 16 rows; BK=64. --------------
__global__ __launch_bounds__(256) void k_tail(
    const unsigned short* __restrict__ attnb, const unsigned short* __restrict__ Wo_b,
    const float* __restrict__ bo, const float* __restrict__ LNf,
    const float* __restrict__ gg, const float* __restrict__ bb,
    const unsigned short* __restrict__ Wm_b, const float* __restrict__ bm,
    const float* __restrict__ Wc, const float* __restrict__ bc,
    float* __restrict__ outs)
{
    __shared__ __align__(16) unsigned short Abuf[16 * 520];
    __shared__ __align__(16) unsigned short Bs[4][128 * 64];
    __shared__ float Zf[16 * 512];
    __shared__ float part[16][4][2];
    const int tid = threadIdx.x, w = tid >> 6, lane = tid & 63;
    const int l15 = lane & 15, quad = lane >> 4, kq = quad * 8;
    const int r0 = blockIdx.x * 16;

#pragma unroll
    for (int c = 0; c < 4; ++c) {
        int row = c * 4 + w;
        g2l16(attnb + (size_t)(r0 + row) * 512 + lane * 8, &Abuf[row * 520]);
    }

    f32x4 acc[8];
#pragma unroll
    for (int i = 0; i < 8; ++i) acc[i] = (f32x4){0.f, 0.f, 0.f, 0.f};

    for (int k0 = 0; k0 < 512; k0 += 64) {
#pragma unroll
        for (int c = 0; c < 16; ++c) {
            int n = w * 128 + c * 8 + (lane >> 3);
            g2l16(Wo_b + (size_t)n * 512 + k0 + (lane & 7) * 8, &Bs[w][c * 512]);
        }
        __syncthreads();
        bf16x8 af0 = *(const bf16x8*)&Abuf[l15 * 520 + k0 + kq];
        bf16x8 af1 = *(const bf16x8*)&Abuf[l15 * 520 + k0 + 32 + kq];
#pragma unroll
        for (int i = 0; i < 8; ++i) {
            bf16x8 b0 = *(const bf16x8*)&Bs[w][(i * 16 + l15) * 64 + kq];
            bf16x8 b1 = *(const bf16x8*)&Bs[w][(i * 16 + l15) * 64 + 32 + kq];
            acc[i] = __builtin_amdgcn_mfma_f32_16x16x32_bf16(af0, b0, acc[i], 0, 0, 0);
            acc[i] = __builtin_amdgcn_mfma_f32_16x16x32_bf16(af1, b1, acc[i], 0, 0, 0);
        }
        __syncthreads();
    }
#pragma unroll
    for (int i = 0; i < 8; ++i) {
        int col = w * 128 + i * 16 + l15;
        float bv = bo[col];
#pragma unroll
        for (int r = 0; r < 4; ++r)
            Zf[(quad * 4 + r) * 512 + col] = acc[i][r] + bv;
    }
    __syncthreads();

    for (int pass = 0; pass < 4; ++pass) {
        int row = pass * 4 + w;
        float v[8];
#pragma unroll
        for (int i = 0; i < 8; ++i)
            v[i] = Zf[row * 512 + lane * 8 + i] + LNf[(size_t)(r0 + row) * 512 + lane * 8 + i];
        float s = 0.f;
#pragma unroll
        for (int i = 0; i < 8; ++i) s += v[i];
#pragma unroll
        for (int m = 32; m; m >>= 1) s += __shfl_xor(s, m, 64);
        float mu = s * (1.f / 512.f);
        float sq = 0.f;
#pragma unroll
        for (int i = 0; i < 8; ++i) { float d = v[i] - mu; sq += d * d; }
#pragma unroll
        for (int m = 32; m; m >>= 1) sq += __shfl_xor(sq, m, 64);
        float rstd = rsqrtf(sq * (1.f / 512.f) + 1e-5f);
#pragma unroll
        for (int i = 0; i < 8; ++i) {
            int col = lane * 8 + i;
            float o = (v[i] - mu) * rstd * gg[col] + bb[col];
            Zf[row * 512 + col] = o;
            Abuf[row * 520 + col] = f2bf(o);
        }
    }
    __syncthreads();

#pragma unroll
    for (int i = 0; i < 8; ++i) acc[i] = (f32x4){0.f, 0.f, 0.f, 0.f};
    for (int k0 = 0; k0 < 512; k0 += 64) {
#pragma unroll
        for (int c = 0; c < 16; ++c) {
            int n = w * 128 + c * 8 + (lane >> 3);
            g2l16(Wm_b + (size_t)n * 512 + k0 + (lane & 7) * 8, &Bs[w][c * 512]);
        }
        __syncthreads();
        bf16x8 af0 = *(const bf16x8*)&Abuf[l15 * 520 + k0 + kq];
        bf16x8 af1 = *(const bf16x8*)&Abuf[l15 * 520 + k0 + 32 + kq];
#pragma unroll
        for (int i = 0; i < 8; ++i) {
            bf16x8 b0 = *(const bf16x8*)&Bs[w][(i * 16 + l15) * 64 + kq];
            bf16x8 b1 = *(const bf16x8*)&Bs[w][(i * 16 + l15) * 64 + 32 + kq];
            acc[i] = __builtin_amdgcn_mfma_f32_16x16x32_bf16(af0, b0, acc[i], 0, 0, 0);
            acc[i] = __builtin_amdgcn_mfma_f32_16x16x32_bf16(af1, b1, acc[i], 0, 0, 0);
        }
        __syncthreads();
    }
    float s0[4] = {0,0,0,0}, s1[4] = {0,0,0,0};
#pragma unroll
    for (int i = 0; i < 8; ++i) {
        int col = w * 128 + i * 16 + l15;
        float wc0 = Wc[col], wc1 = Wc[512 + col], bmv = bm[col];
#pragma unroll
        for (int r = 0; r < 4; ++r) {
            float v = acc[i][r] + bmv;
            float x = 0.5f * v * (1.f + erff(v * 0.70710678118654752f))
                    + Zf[(quad * 4 + r) * 512 + col];
            s0[r] += x * wc0; s1[r] += x * wc1;
        }
    }
#pragma unroll
    for (int off = 8; off; off >>= 1)
#pragma unroll
        for (int r = 0; r < 4; ++r) {
            s0[r] += __shfl_xor(s0[r], off, 16);
            s1[r] += __shfl_xor(s1[r], off, 16);
        }
    if (l15 == 0)
#pragma unroll
        for (int r = 0; r < 4; ++r) {
            part[quad * 4 + r][w][0] = s0[r];
            part[quad * 4 + r][w][1] = s1[r];
        }
    __syncthreads();
    if (tid < 32) {
        int row = tid >> 1, c = tid & 1;
        float s = part[row][0][c] + part[row][1][c] + part[row][2][c] + part[row][3][c];
        outs[(r0 + row) * 2 + c] = s + bc[c];
    }
}

// --- final gather; reduces hist partials + newv per block -------------------
__global__ __launch_bounds__(256) void k_out(
    const int* __restrict__ masks, const float* __restrict__ probs,
    const float* __restrict__ hpart, const float* __restrict__ outs,
    float* __restrict__ out)
{
    __shared__ float ps[68];
    __shared__ float nv[17 * 3];
    int tid = threadIdx.x;
    int b = blockIdx.x >> 8;
    if (tid < 68) {
        float s = 0.f;
        const float* pp = hpart + (size_t)b * 64 * 68 + tid;
        for (int c = 0; c < 64; ++c) s += pp[c * 68];
        ps[tid] = s;
    }
    __syncthreads();
    if (tid < 17) {
        int lab = tid;
        if (lab == 0) { nv[0] = 0.f; nv[1] = 0.f; nv[2] = 0.f; }
        else {
            float c  = fmaxf(ps[51 + lab], 1.f);
            float m0 = ps[lab * 3 + 0] / c + 1e-6f;
            float m1 = ps[lab * 3 + 1] / c + 1e-6f;
            float m2 = ps[lab * 3 + 2] / c + 1e-6f;
            int p = lab - 1;
            float o0 = outs[(b * 16 + p) * 2 + 0], o1 = outs[(b * 16 + p) * 2 + 1];
            nv[lab * 3 + 0] = m0 / (0.5f * (m1 + m2)) * (0.5f * (o0 + o1));
            nv[lab * 3 + 1] = o0;
            nv[lab * 3 + 2] = o1;
        }
    }
    __syncthreads();
    int px = (blockIdx.x & 255) * 256 + tid;
    int gl = b * 65536 + px;
    int lab = masks[gl];
    if (lab > 0) {
        out[(size_t)(b*3+0)*65536 + px] = nv[lab*3+0];
        out[(size_t)(b*3+1)*65536 + px] = nv[lab*3+1];
        out[(size_t)(b*3+2)*65536 + px] = nv[lab*3+2];
    } else {
        out[(size_t)(b*3+0)*65536 + px] = probs[(size_t)(b*3+0)*65536 + px];
        out[(size_t)(b*3+1)*65536 + px] = probs[(size_t)(b*3+1)*65536 + px];
        out[(size_t)(b*3+2)*65536 + px] = probs[(size_t)(b*3+2)*65536 + px];
    }
}

// ---------------------------------------------------------------------------
extern "C" void kernel_launch(void* const* d_in, const int* in_sizes, int n_in,
                              void* d_out, int out_size, void* d_ws, size_t ws_size,
                              hipStream_t stream)
{
    const float* features = (const float*)d_in[0];
    const float* probs    = (const float*)d_in[1];
    const float* patches  = (const float*)d_in[2];
    const int*   masks    = (const int*)d_in[3];
    const float* ln_g     = (const float*)d_in[4];
    const float* ln_b     = (const float*)d_in[5];
    const float* Wr       = (const float*)d_in[6];
    const float* br       = (const float*)d_in[7];
    const float* Wqkv     = (const float*)d_in[8];
    const float* bqkv     = (const float*)d_in[9];
    const float* Wo       = (const float*)d_in[10];
    const float* bo       = (const float*)d_in[11];
    const float* Wm       = (const float*)d_in[12];
    const float* bm       = (const float*)d_in[13];
    const float* Wc       = (const float*)d_in[14];
    const float* bc       = (const float*)d_in[15];
    float* out = (float*)d_out;

    char* w = (char*)d_ws;
    size_t off = 0;
    auto alloc = [&](size_t bytes) -> char* {
        char* p = w + off;
        off += (bytes + 255) & ~(size_t)255;
        return p;
    };
    unsigned short* Gp     = (unsigned short*)alloc((size_t)2097152 * 2);
    unsigned short* Xb     = (unsigned short*)alloc((size_t)128 * 4096 * 2);
    unsigned short* Wr_b   = (unsigned short*)alloc((size_t)2097152 * 2);
    unsigned short* Wqkv_b = (unsigned short*)alloc((size_t)786432 * 2);
    unsigned short* Wo_b   = (unsigned short*)alloc((size_t)262144 * 2);
    unsigned short* Wm_b   = (unsigned short*)alloc((size_t)262144 * 2);
    float* Yp   = (float*)alloc((size_t)8 * 1928 * 512 * 4);   // split-K=8
    float* LNf  = (float*)alloc((size_t)128 * 512 * 4);
    unsigned short* LNb  = (unsigned short*)alloc((size_t)1928 * 512 * 2);
    unsigned short* QKVb = (unsigned short*)alloc((size_t)1928 * 1536 * 2);
    unsigned short* attnb = (unsigned short*)alloc((size_t)65536 * 2);
    float* outsB = (float*)alloc((size_t)256 * 4);
    float* hpart = (float*)alloc((size_t)512 * 68 * 4);

    // 1: pools + weight cvt + hist partials (conflict-free)
    k_prep<<<6912, 256, 0, stream>>>(features, patches, Wr, Wqkv, Wo, Wm,
                                     masks, probs,
                                     Gp, Xb, Wr_b, Wqkv_b, Wo_b, Wm_b, hpart);
    // 2: GEMM1 split-K=8 with fused gather (512 blocks)
    k_gemm128<true><<<dim3(4, 16, 8), 256, 0, stream>>>(
        Xb, Gp, Wr_b, Yp, 1928, 512, 4096, 512);
    // 3: reduce + br + LN1
    k_lnred<<<482, 256, 0, stream>>>(Yp, br, ln_g, ln_b, LNf, LNb, 1928, 8);
    // 4: QKV = LNb @ Wqkv^T + bqkv, bf16 out, 64x64 tiles (744 blocks)
    k_gemm64<<<dim3(24, 31), 256, 0, stream>>>(LNb, Wqkv_b, bqkv, QKVb, 1928, 1536, 512);
    // 5: attention (256 blocks)
    k_attn<<<dim3(8, 8, 4), 256, 0, stream>>>(QKVb, attnb);
    // 6: fused tail (Wo + LN + Wm + gelu + Wc), BK=64
    k_tail<<<8, 256, 0, stream>>>(attnb, Wo_b, bo, LNf, ln_g, ln_b,
                                  Wm_b, bm, Wc, bc, outsB);
    // 7: final gather (hist reduce + newv per block)
    k_out<<<2048, 256, 0, stream>>>(masks, probs, hpart, outsB, out);
}

// Round 9
// 339.495 us; speedup vs baseline: 1.1105x; 1.1105x over previous
//
#include <hip/hip_runtime.h>
#include <stdint.h>

// ---------------------------------------------------------------------------
// WeedLayer. B=8, C=64, H=W=256, PD=32, STRIDE=16 -> n=15, L=225, P=16, E=512,
// HEADS=8, hd=64, fv=4096. X = [patches(128); blocks(1800)] = 1928 rows.
// R9: k_prep phase ORDER changed -> hist blocks FIRST so their memory latency
//     hides under the feature-pool streaming phase (R8 post-mortem: hist was
//     a ~30us exposed latency tail). 7 dispatches.
// ---------------------------------------------------------------------------

typedef __attribute__((ext_vector_type(8))) short bf16x8;
typedef __attribute__((ext_vector_type(4))) float f32x4;

__device__ __forceinline__ unsigned short f2bf(float x) {
    union { float f; unsigned u; } v; v.f = x;
    unsigned r = v.u + 0x7FFFu + ((v.u >> 16) & 1u);   // RNE
    return (unsigned short)(r >> 16);
}
__device__ __forceinline__ float bf2f(unsigned short x) {
    union { unsigned u; float f; } v; v.u = ((unsigned)x) << 16; return v.f;
}

__device__ __forceinline__ void g2l16(const unsigned short* g, unsigned short* l) {
    __builtin_amdgcn_global_load_lds(
        (const __attribute__((address_space(1))) unsigned int*)g,
        (__attribute__((address_space(3))) unsigned int*)l, 16, 0, 0);
}

// --- K_prep: hist | pool_features | pool_patches | weight f2bf --------------
// blocks: [0,512) hist  [512,2560) features  [2560,3584) patches
//         [3584,6912) weights
__global__ __launch_bounds__(256) void k_prep(
    const float* __restrict__ f, const float* __restrict__ p,
    const float* __restrict__ Wr, const float* __restrict__ Wqkv,
    const float* __restrict__ Wo, const float* __restrict__ Wm,
    const int* __restrict__ masks, const float* __restrict__ probs,
    unsigned short* __restrict__ gp, unsigned short* __restrict__ Xb,
    unsigned short* __restrict__ oWr, unsigned short* __restrict__ oWqkv,
    unsigned short* __restrict__ oWo, unsigned short* __restrict__ oWm,
    float* __restrict__ hpart)
{
    int blk = blockIdx.x, tid = threadIdx.x;
    if (blk < 512) {
        // hist: 64 private copies (one per lane id), stride 69 (conflict-free)
        __shared__ float ls[64 * 69];                    // 17.7 KB
        int hb = blk;
        int b = hb >> 6, chunk = hb & 63;
        int lane = tid & 63;
        float* my = &ls[lane * 69];
        for (int i = tid; i < 64 * 69; i += 256) ls[i] = 0.f;
        __syncthreads();
        int base = chunk * 1024;
        for (int it = 0; it < 4; ++it) {
            int px = base + it * 256 + tid;
            int lab = masks[b * 65536 + px];
            atomicAdd(&my[lab * 3 + 0], probs[(size_t)(b * 3 + 0) * 65536 + px]);
            atomicAdd(&my[lab * 3 + 1], probs[(size_t)(b * 3 + 1) * 65536 + px]);
            atomicAdd(&my[lab * 3 + 2], probs[(size_t)(b * 3 + 2) * 65536 + px]);
            atomicAdd(&my[51 + lab], 1.f);
        }
        __syncthreads();
        if (tid < 68) {
            float s = 0.f;
            for (int c = 0; c < 64; ++c) s += ls[c * 69 + tid];
            hpart[(size_t)hb * 68 + tid] = s;
        }
    } else if (blk < 2560) {
        // feature pool: 2 output rows per thread (16 outstanding float4 loads)
        unsigned t = (blk - 512) * 256u + tid;           // 524,288 units
        unsigned q2 = t & 63u, rh = (t >> 6) & 63u, g = (t >> 12) & 15u, b = t >> 16;
        const float4* f4 = (const float4*)f;
        unsigned cb = b * 64u + g * 4u;
        float s[2][2] = {{0.f, 0.f}, {0.f, 0.f}};
#pragma unroll
        for (int rr = 0; rr < 2; ++rr) {
            unsigned r = rh + rr * 64u;
#pragma unroll
            for (int j = 0; j < 4; ++j)
#pragma unroll
                for (int a = 0; a < 2; ++a) {
                    float4 v = f4[((cb + j) * 256u + 2u * r + a) * 64u + q2];
                    s[rr][0] += v.x + v.y; s[rr][1] += v.z + v.w;
                }
        }
#pragma unroll
        for (int rr = 0; rr < 2; ++rr) {
            unsigned r = rh + rr * 64u;
            ushort2 o; o.x = f2bf(s[rr][0] * 0.0625f); o.y = f2bf(s[rr][1] * 0.0625f);
            ((ushort2*)gp)[((b * 16u + g) * 128u + r) * 64u + q2] = o;
        }
    } else if (blk < 3584) {
        // patch pool: 2 outputs per thread via float4 loads
        unsigned t = (blk - 2560) * 256u + tid;          // 262,144 units
        unsigned q4 = t & 7u, r = (t >> 3) & 15u, g = (t >> 7) & 15u, row = t >> 11;
        const float4* p4 = (const float4*)p;
        float s0 = 0.f, s1 = 0.f;
        unsigned cb = row * 64u + g * 4u;
#pragma unroll
        for (int j = 0; j < 4; ++j)
#pragma unroll
            for (int a = 0; a < 2; ++a) {
                float4 v = p4[((cb + j) * 32u + 2u * r + a) * 8u + q4];
                s0 += v.x + v.y; s1 += v.z + v.w;
            }
        ushort2 o; o.x = f2bf(s0 * 0.0625f); o.y = f2bf(s1 * 0.0625f);
        *(ushort2*)(Xb + (size_t)row * 4096 + g * 256 + r * 16 + 2 * q4) = o;
    } else {
        int t = (blk - 3584) * 256 + tid;                // 851,968 float4 groups
        const float* src; unsigned short* dst; int i;
        if (t < 524288)      { src = Wr;   dst = oWr;   i = t; }
        else if (t < 720896) { src = Wqkv; dst = oWqkv; i = t - 524288; }
        else if (t < 786432) { src = Wo;   dst = oWo;   i = t - 720896; }
        else                 { src = Wm;   dst = oWm;   i = t - 786432; }
        float4 v = ((const float4*)src)[i];
        ushort4 o;
        o.x = f2bf(v.x); o.y = f2bf(v.y); o.z = f2bf(v.z); o.w = f2bf(v.w);
        ((ushort4*)dst)[i] = o;
    }
}

// --- 128x128-tile bf16 NT GEMM; GATHER reads block rows from Gp -------------
template<bool GATHER>
__global__ __launch_bounds__(256) void k_gemm128(
    const unsigned short* __restrict__ A, const unsigned short* __restrict__ Gp,
    const unsigned short* __restrict__ Bw,
    float* __restrict__ C, int M, int N, int K, int klen)
{
    __shared__ __align__(16) unsigned short As[128 * 32];
    __shared__ __align__(16) unsigned short Bs[128 * 32];
    const int tid = threadIdx.x, w = tid >> 6, lane = tid & 63;
    const int nt = blockIdx.x, mt = blockIdx.y, ks = blockIdx.z;
    const int kbase = ks * klen;
    const int l15 = lane & 15, kq = (lane >> 4) * 8;
    const int wm = (w >> 1) * 64, wn = (w & 1) * 64;
    const int srow0 = w * 32, lrow = lane >> 2, lcol = (lane & 3) * 8;

    size_t arowbase[2]; bool apatch[2];
#pragma unroll
    for (int c = 0; c < 2; ++c) {
        int r = srow0 + c * 16 + lrow;
        int ga = mt * 128 + r; if (ga > M - 1) ga = M - 1;
        if (GATHER && ga >= 128) {
            int rr = ga - 128;
            int bb = rr / 225, ij = rr - bb * 225;
            int ii = ij / 15, jj = ij - ii * 15;
            arowbase[c] = (size_t)bb * 262144 + ii * 1024 + jj * 8;
            apatch[c] = false;
        } else {
            arowbase[c] = (size_t)ga * K;
            apatch[c] = true;
        }
    }
    const int brow0 = nt * 128;

    f32x4 acc[4][4];
#pragma unroll
    for (int i = 0; i < 4; ++i)
#pragma unroll
        for (int j = 0; j < 4; ++j) acc[i][j] = (f32x4){0.f, 0.f, 0.f, 0.f};

    for (int k0 = 0; k0 < klen; k0 += 32) {
        int kcol = kbase + k0 + lcol;
#pragma unroll
        for (int c = 0; c < 2; ++c) {
            const unsigned short* gp_a;
            if (!GATHER || apatch[c]) {
                gp_a = A + arowbase[c] + kcol;
            } else {
                gp_a = Gp + arowbase[c] + ((size_t)(kcol >> 8) << 14)
                     + (((kcol >> 4) & 15) << 7) + (kcol & 15);
            }
            g2l16(gp_a, &As[(srow0 + c * 16) * 32]);
            g2l16(Bw + (size_t)(brow0 + srow0 + c * 16 + lrow) * K + kcol,
                  &Bs[(srow0 + c * 16) * 32]);
        }
        __syncthreads();
        bf16x8 af[4], bf[4];
#pragma unroll
        for (int i = 0; i < 4; ++i) {
            af[i] = *(const bf16x8*)&As[(wm + 16 * i + l15) * 32 + kq];
            bf[i] = *(const bf16x8*)&Bs[(wn + 16 * i + l15) * 32 + kq];
        }
#pragma unroll
        for (int i = 0; i < 4; ++i)
#pragma unroll
            for (int j = 0; j < 4; ++j)
                acc[i][j] = __builtin_amdgcn_mfma_f32_16x16x32_bf16(af[i], bf[j], acc[i][j], 0, 0, 0);
        __syncthreads();
    }
    float* Cp = C + (size_t)ks * M * N;
#pragma unroll
    for (int i = 0; i < 4; ++i) {
        int rowb = mt * 128 + wm + i * 16 + (lane >> 4) * 4;
#pragma unroll
        for (int j = 0; j < 4; ++j) {
            int col = nt * 128 + wn + j * 16 + l15;
#pragma unroll
            for (int r = 0; r < 4; ++r) {
                int row = rowb + r;
                if (row < M) Cp[(size_t)row * N + col] = acc[i][j][r];
            }
        }
    }
}

// --- 64x64-tile bf16 NT GEMM, bias, bf16 out (QKV: high occupancy) ----------
__global__ __launch_bounds__(256) void k_gemm64(
    const unsigned short* __restrict__ A, const unsigned short* __restrict__ Bw,
    const float* __restrict__ bias, unsigned short* __restrict__ Cb,
    int M, int N, int K)
{
    __shared__ __align__(16) unsigned short As[64 * 32];
    __shared__ __align__(16) unsigned short Bs[64 * 32];
    const int tid = threadIdx.x, w = tid >> 6, lane = tid & 63;
    const int bm = blockIdx.y, bn = blockIdx.x;
    const int wm = (w >> 1) * 32, wn = (w & 1) * 32;
    const int l15 = lane & 15, kq = (lane >> 4) * 8;
    const int lrow = lane >> 2, lcol = (lane & 3) * 8;
    int ga = bm * 64 + w * 16 + lrow; if (ga > M - 1) ga = M - 1;
    const unsigned short* Ap = A + (size_t)ga * K;
    const unsigned short* Bp = Bw + (size_t)(bn * 64 + w * 16 + lrow) * K;

    f32x4 acc[2][2];
#pragma unroll
    for (int i = 0; i < 2; ++i)
#pragma unroll
        for (int j = 0; j < 2; ++j) acc[i][j] = (f32x4){0.f, 0.f, 0.f, 0.f};

    for (int k0 = 0; k0 < K; k0 += 32) {
        g2l16(Ap + k0 + lcol, &As[(w * 16) * 32]);
        g2l16(Bp + k0 + lcol, &Bs[(w * 16) * 32]);
        __syncthreads();
        bf16x8 a0 = *(const bf16x8*)&As[(wm + l15) * 32 + kq];
        bf16x8 a1 = *(const bf16x8*)&As[(wm + 16 + l15) * 32 + kq];
        bf16x8 b0 = *(const bf16x8*)&Bs[(wn + l15) * 32 + kq];
        bf16x8 b1 = *(const bf16x8*)&Bs[(wn + 16 + l15) * 32 + kq];
        acc[0][0] = __builtin_amdgcn_mfma_f32_16x16x32_bf16(a0, b0, acc[0][0], 0, 0, 0);
        acc[0][1] = __builtin_amdgcn_mfma_f32_16x16x32_bf16(a0, b1, acc[0][1], 0, 0, 0);
        acc[1][0] = __builtin_amdgcn_mfma_f32_16x16x32_bf16(a1, b0, acc[1][0], 0, 0, 0);
        acc[1][1] = __builtin_amdgcn_mfma_f32_16x16x32_bf16(a1, b1, acc[1][1], 0, 0, 0);
        __syncthreads();
    }
#pragma unroll
    for (int it = 0; it < 2; ++it) {
        int rowb = bm * 64 + wm + it * 16 + (lane >> 4) * 4;
#pragma unroll
        for (int iu = 0; iu < 2; ++iu) {
            int col = bn * 64 + wn + iu * 16 + l15;
            float bv = bias[col];
#pragma unroll
            for (int r = 0; r < 4; ++r) {
                int row = rowb + r;
                if (row < M) Cb[(size_t)row * N + col] = f2bf(acc[it][iu][r] + bv);
            }
        }
    }
}

// --- nsplit-partial reduce + bias + LayerNorm (wave/row) --------------------
__global__ __launch_bounds__(256) void k_lnred(
    const float* __restrict__ Yp, const float* __restrict__ br,
    const float* __restrict__ gg, const float* __restrict__ bb,
    float* __restrict__ outF, unsigned short* __restrict__ outB,
    int rows, int nsplit)
{
    int wave = threadIdx.x >> 6, lane = threadIdx.x & 63;
    int row = blockIdx.x * 4 + wave;
    if (row >= rows) return;
    size_t base = (size_t)row * 512 + lane * 8;
    float v[8];
    { const float* bp = br + lane * 8;
      float4 a = *(const float4*)bp, b = *(const float4*)(bp + 4);
      v[0]=a.x; v[1]=a.y; v[2]=a.z; v[3]=a.w; v[4]=b.x; v[5]=b.y; v[6]=b.z; v[7]=b.w; }
    for (int s = 0; s < nsplit; ++s) {
        const float* xp = Yp + (size_t)s * rows * 512 + base;
        float4 a = *(const float4*)xp, b = *(const float4*)(xp + 4);
        v[0]+=a.x; v[1]+=a.y; v[2]+=a.z; v[3]+=a.w; v[4]+=b.x; v[5]+=b.y; v[6]+=b.z; v[7]+=b.w;
    }
    float s = 0.f;
#pragma unroll
    for (int i = 0; i < 8; ++i) s += v[i];
#pragma unroll
    for (int m = 32; m; m >>= 1) s += __shfl_xor(s, m, 64);
    float mu = s * (1.f / 512.f);
    float sq = 0.f;
#pragma unroll
    for (int i = 0; i < 8; ++i) { float d = v[i] - mu; sq += d * d; }
#pragma unroll
    for (int m = 32; m; m >>= 1) sq += __shfl_xor(sq, m, 64);
    float rstd = rsqrtf(sq * (1.f / 512.f) + 1e-5f);
    const float* gp = gg + lane * 8;
    const float* bp2 = bb + lane * 8;
    float4 g0 = *(const float4*)gp, g1 = *(const float4*)(gp + 4);
    float4 b0 = *(const float4*)bp2, b1 = *(const float4*)(bp2 + 4);
    float ga[8] = {g0.x,g0.y,g0.z,g0.w,g1.x,g1.y,g1.z,g1.w};
    float ba[8] = {b0.x,b0.y,b0.z,b0.w,b1.x,b1.y,b1.z,b1.w};
    float o[8];
#pragma unroll
    for (int i = 0; i < 8; ++i) o[i] = (v[i] - mu) * rstd * ga[i] + ba[i];
    if (row < 128) {
        float* ofp = outF + base;
        float4 w0; w0.x=o[0]; w0.y=o[1]; w0.z=o[2]; w0.w=o[3];
        float4 w1; w1.x=o[4]; w1.y=o[5]; w1.z=o[6]; w1.w=o[7];
        *(float4*)ofp = w0; *(float4*)(ofp + 4) = w1;
    }
    unsigned short* obp = outB + base;
    ushort4 u0, u1;
    u0.x=f2bf(o[0]); u0.y=f2bf(o[1]); u0.z=f2bf(o[2]); u0.w=f2bf(o[3]);
    u1.x=f2bf(o[4]); u1.y=f2bf(o[5]); u1.z=f2bf(o[6]); u1.w=f2bf(o[7]);
    ((ushort4*)obp)[0] = u0; ((ushort4*)obp)[1] = u1;
}

// --- attention: grid (8b, 8h, 4pz); QKV bf16 [1928 x 1536] ------------------
__global__ __launch_bounds__(256) void k_attn(
    const unsigned short* __restrict__ QKVb, unsigned short* __restrict__ attn_bf)
{
    const int b = blockIdx.x, h = blockIdx.y, pz = blockIdx.z;
    __shared__ __align__(16) float qs[4 * 64];
    __shared__ __align__(16) unsigned short Ks[225 * 68];
    __shared__ __align__(16) unsigned short Vs[225 * 64];
    __shared__ float sc[4 * 225];
    const int t = threadIdx.x;

    {
        int p = t >> 6, d = t & 63;
        qs[t] = bf2f(QKVb[(size_t)(b * 16 + pz * 4 + p) * 1536 + h * 64 + d]);
    }
    for (int i = t; i < 1800; i += 256) {
        int l = i >> 3, d8 = (i & 7) * 8;
        size_t base = (size_t)(128 + b * 225 + l) * 1536 + h * 64 + d8;
        uint4 kk4 = *(const uint4*)(QKVb + base + 512);
        *(uint2*)&Ks[l * 68 + d8]     = make_uint2(kk4.x, kk4.y);
        *(uint2*)&Ks[l * 68 + d8 + 4] = make_uint2(kk4.z, kk4.w);
        *(uint4*)&Vs[l * 64 + d8] = *(const uint4*)(QKVb + base + 1024);
    }
    __syncthreads();
    for (int i = t; i < 900; i += 256) {
        int p = i / 225, l = i - p * 225;
        const ushort4* k4 = (const ushort4*)&Ks[l * 68];
        const float4* q4 = (const float4*)&qs[p * 64];
        float s = 0.f;
#pragma unroll
        for (int d = 0; d < 16; ++d) {
            ushort4 kk = k4[d]; float4 qq = q4[d];
            s += bf2f(kk.x) * qq.x + bf2f(kk.y) * qq.y
               + bf2f(kk.z) * qq.z + bf2f(kk.w) * qq.w;
        }
        sc[p * 225 + l] = s * 0.125f;
    }
    __syncthreads();
    const int lane = t & 63, wave = t >> 6;
    {
        float* row = &sc[wave * 225];
        float m = -1e30f;
        for (int l = lane; l < 225; l += 64) m = fmaxf(m, row[l]);
#pragma unroll
        for (int off = 32; off; off >>= 1) m = fmaxf(m, __shfl_xor(m, off, 64));
        float s = 0.f;
        for (int l = lane; l < 225; l += 64) { float e = __expf(row[l] - m); row[l] = e; s += e; }
#pragma unroll
        for (int off = 32; off; off >>= 1) s += __shfl_xor(s, off, 64);
        float inv = 1.f / s;
        for (int l = lane; l < 225; l += 64) row[l] *= inv;
    }
    __syncthreads();
    {
        float o = 0.f;
        const float* scp = &sc[wave * 225];
        for (int l = 0; l < 225; ++l) o += scp[l] * bf2f(Vs[l * 64 + lane]);
        attn_bf[(size_t)(b * 16 + pz * 4 + wave) * 512 + h * 64 + lane] = f2bf(o);
    }
}

// --- tail: Zo=attnb@Wo^T+bo; res=LN(Zo+pe); M1=res@Wm^T+bm;
//     outs=(gelu(M1)+res)@Wc^T+bc.  8 blocks x 16 rows; BK=64. --------------
__global__ __launch_bounds__(256) void k_tail(
    const unsigned short* __restrict__ attnb, const unsigned short* __restrict__ Wo_b,
    const float* __restrict__ bo, const float* __restrict__ LNf,
    const float* __restrict__ gg, const float* __restrict__ bb,
    const unsigned short* __restrict__ Wm_b, const float* __restrict__ bm,
    const float* __restrict__ Wc, const float* __restrict__ bc,
    float* __restrict__ outs)
{
    __shared__ __align__(16) unsigned short Abuf[16 * 520];
    __shared__ __align__(16) unsigned short Bs[4][128 * 64];
    __shared__ float Zf[16 * 512];
    __shared__ float part[16][4][2];
    const int tid = threadIdx.x, w = tid >> 6, lane = tid & 63;
    const int l15 = lane & 15, quad = lane >> 4, kq = quad * 8;
    const int r0 = blockIdx.x * 16;

#pragma unroll
    for (int c = 0; c < 4; ++c) {
        int row = c * 4 + w;
        g2l16(attnb + (size_t)(r0 + row) * 512 + lane * 8, &Abuf[row * 520]);
    }

    f32x4 acc[8];
#pragma unroll
    for (int i = 0; i < 8; ++i) acc[i] = (f32x4){0.f, 0.f, 0.f, 0.f};

    for (int k0 = 0; k0 < 512; k0 += 64) {
#pragma unroll
        for (int c = 0; c < 16; ++c) {
            int n = w * 128 + c * 8 + (lane >> 3);
            g2l16(Wo_b + (size_t)n * 512 + k0 + (lane & 7) * 8, &Bs[w][c * 512]);
        }
        __syncthreads();
        bf16x8 af0 = *(const bf16x8*)&Abuf[l15 * 520 + k0 + kq];
        bf16x8 af1 = *(const bf16x8*)&Abuf[l15 * 520 + k0 + 32 + kq];
#pragma unroll
        for (int i = 0; i < 8; ++i) {
            bf16x8 b0 = *(const bf16x8*)&Bs[w][(i * 16 + l15) * 64 + kq];
            bf16x8 b1 = *(const bf16x8*)&Bs[w][(i * 16 + l15) * 64 + 32 + kq];
            acc[i] = __builtin_amdgcn_mfma_f32_16x16x32_bf16(af0, b0, acc[i], 0, 0, 0);
            acc[i] = __builtin_amdgcn_mfma_f32_16x16x32_bf16(af1, b1, acc[i], 0, 0, 0);
        }
        __syncthreads();
    }
#pragma unroll
    for (int i = 0; i < 8; ++i) {
        int col = w * 128 + i * 16 + l15;
        float bv = bo[col];
#pragma unroll
        for (int r = 0; r < 4; ++r)
            Zf[(quad * 4 + r) * 512 + col] = acc[i][r] + bv;
    }
    __syncthreads();

    for (int pass = 0; pass < 4; ++pass) {
        int row = pass * 4 + w;
        float v[8];
#pragma unroll
        for (int i = 0; i < 8; ++i)
            v[i] = Zf[row * 512 + lane * 8 + i] + LNf[(size_t)(r0 + row) * 512 + lane * 8 + i];
        float s = 0.f;
#pragma unroll
        for (int i = 0; i < 8; ++i) s += v[i];
#pragma unroll
        for (int m = 32; m; m >>= 1) s += __shfl_xor(s, m, 64);
        float mu = s * (1.f / 512.f);
        float sq = 0.f;
#pragma unroll
        for (int i = 0; i < 8; ++i) { float d = v[i] - mu; sq += d * d; }
#pragma unroll
        for (int m = 32; m; m >>= 1) sq += __shfl_xor(sq, m, 64);
        float rstd = rsqrtf(sq * (1.f / 512.f) + 1e-5f);
#pragma unroll
        for (int i = 0; i < 8; ++i) {
            int col = lane * 8 + i;
            float o = (v[i] - mu) * rstd * gg[col] + bb[col];
            Zf[row * 512 + col] = o;
            Abuf[row * 520 + col] = f2bf(o);
        }
    }
    __syncthreads();

#pragma unroll
    for (int i = 0; i < 8; ++i) acc[i] = (f32x4){0.f, 0.f, 0.f, 0.f};
    for (int k0 = 0; k0 < 512; k0 += 64) {
#pragma unroll
        for (int c = 0; c < 16; ++c) {
            int n = w * 128 + c * 8 + (lane >> 3);
            g2l16(Wm_b + (size_t)n * 512 + k0 + (lane & 7) * 8, &Bs[w][c * 512]);
        }
        __syncthreads();
        bf16x8 af0 = *(const bf16x8*)&Abuf[l15 * 520 + k0 + kq];
        bf16x8 af1 = *(const bf16x8*)&Abuf[l15 * 520 + k0 + 32 + kq];
#pragma unroll
        for (int i = 0; i < 8; ++i) {
            bf16x8 b0 = *(const bf16x8*)&Bs[w][(i * 16 + l15) * 64 + kq];
            bf16x8 b1 = *(const bf16x8*)&Bs[w][(i * 16 + l15) * 64 + 32 + kq];
            acc[i] = __builtin_amdgcn_mfma_f32_16x16x32_bf16(af0, b0, acc[i], 0, 0, 0);
            acc[i] = __builtin_amdgcn_mfma_f32_16x16x32_bf16(af1, b1, acc[i], 0, 0, 0);
        }
        __syncthreads();
    }
    float s0[4] = {0,0,0,0}, s1[4] = {0,0,0,0};
#pragma unroll
    for (int i = 0; i < 8; ++i) {
        int col = w * 128 + i * 16 + l15;
        float wc0 = Wc[col], wc1 = Wc[512 + col], bmv = bm[col];
#pragma unroll
        for (int r = 0; r < 4; ++r) {
            float v = acc[i][r] + bmv;
            float x = 0.5f * v * (1.f + erff(v * 0.70710678118654752f))
                    + Zf[(quad * 4 + r) * 512 + col];
            s0[r] += x * wc0; s1[r] += x * wc1;
        }
    }
#pragma unroll
    for (int off = 8; off; off >>= 1)
#pragma unroll
        for (int r = 0; r < 4; ++r) {
            s0[r] += __shfl_xor(s0[r], off, 16);
            s1[r] += __shfl_xor(s1[r], off, 16);
        }
    if (l15 == 0)
#pragma unroll
        for (int r = 0; r < 4; ++r) {
            part[quad * 4 + r][w][0] = s0[r];
            part[quad * 4 + r][w][1] = s1[r];
        }
    __syncthreads();
    if (tid < 32) {
        int row = tid >> 1, c = tid & 1;
        float s = part[row][0][c] + part[row][1][c] + part[row][2][c] + part[row][3][c];
        outs[(r0 + row) * 2 + c] = s + bc[c];
    }
}

// --- final gather; reduces hist partials + newv per block -------------------
__global__ __launch_bounds__(256) void k_out(
    const int* __restrict__ masks, const float* __restrict__ probs,
    const float* __restrict__ hpart, const float* __restrict__ outs,
    float* __restrict__ out)
{
    __shared__ float ps[68];
    __shared__ float nv[17 * 3];
    int tid = threadIdx.x;
    int b = blockIdx.x >> 8;
    if (tid < 68) {
        float s = 0.f;
        const float* pp = hpart + (size_t)b * 64 * 68 + tid;
        for (int c = 0; c < 64; ++c) s += pp[c * 68];
        ps[tid] = s;
    }
    __syncthreads();
    if (tid < 17) {
        int lab = tid;
        if (lab == 0) { nv[0] = 0.f; nv[1] = 0.f; nv[2] = 0.f; }
        else {
            float c  = fmaxf(ps[51 + lab], 1.f);
            float m0 = ps[lab * 3 + 0] / c + 1e-6f;
            float m1 = ps[lab * 3 + 1] / c + 1e-6f;
            float m2 = ps[lab * 3 + 2] / c + 1e-6f;
            int p = lab - 1;
            float o0 = outs[(b * 16 + p) * 2 + 0], o1 = outs[(b * 16 + p) * 2 + 1];
            nv[lab * 3 + 0] = m0 / (0.5f * (m1 + m2)) * (0.5f * (o0 + o1));
            nv[lab * 3 + 1] = o0;
            nv[lab * 3 + 2] = o1;
        }
    }
    __syncthreads();
    int px = (blockIdx.x & 255) * 256 + tid;
    int gl = b * 65536 + px;
    int lab = masks[gl];
    if (lab > 0) {
        out[(size_t)(b*3+0)*65536 + px] = nv[lab*3+0];
        out[(size_t)(b*3+1)*65536 + px] = nv[lab*3+1];
        out[(size_t)(b*3+2)*65536 + px] = nv[lab*3+2];
    } else {
        out[(size_t)(b*3+0)*65536 + px] = probs[(size_t)(b*3+0)*65536 + px];
        out[(size_t)(b*3+1)*65536 + px] = probs[(size_t)(b*3+1)*65536 + px];
        out[(size_t)(b*3+2)*65536 + px] = probs[(size_t)(b*3+2)*65536 + px];
    }
}

// ---------------------------------------------------------------------------
extern "C" void kernel_launch(void* const* d_in, const int* in_sizes, int n_in,
                              void* d_out, int out_size, void* d_ws, size_t ws_size,
                              hipStream_t stream)
{
    const float* features = (const float*)d_in[0];
    const float* probs    = (const float*)d_in[1];
    const float* patches  = (const float*)d_in[2];
    const int*   masks    = (const int*)d_in[3];
    const float* ln_g     = (const float*)d_in[4];
    const float* ln_b     = (const float*)d_in[5];
    const float* Wr       = (const float*)d_in[6];
    const float* br       = (const float*)d_in[7];
    const float* Wqkv     = (const float*)d_in[8];
    const float* bqkv     = (const float*)d_in[9];
    const float* Wo       = (const float*)d_in[10];
    const float* bo       = (const float*)d_in[11];
    const float* Wm       = (const float*)d_in[12];
    const float* bm       = (const float*)d_in[13];
    const float* Wc       = (const float*)d_in[14];
    const float* bc       = (const float*)d_in[15];
    float* out = (float*)d_out;

    char* w = (char*)d_ws;
    size_t off = 0;
    auto alloc = [&](size_t bytes) -> char* {
        char* p = w + off;
        off += (bytes + 255) & ~(size_t)255;
        return p;
    };
    unsigned short* Gp     = (unsigned short*)alloc((size_t)2097152 * 2);
    unsigned short* Xb     = (unsigned short*)alloc((size_t)128 * 4096 * 2);
    unsigned short* Wr_b   = (unsigned short*)alloc((size_t)2097152 * 2);
    unsigned short* Wqkv_b = (unsigned short*)alloc((size_t)786432 * 2);
    unsigned short* Wo_b   = (unsigned short*)alloc((size_t)262144 * 2);
    unsigned short* Wm_b   = (unsigned short*)alloc((size_t)262144 * 2);
    float* Yp   = (float*)alloc((size_t)8 * 1928 * 512 * 4);   // split-K=8
    float* LNf  = (float*)alloc((size_t)128 * 512 * 4);
    unsigned short* LNb  = (unsigned short*)alloc((size_t)1928 * 512 * 2);
    unsigned short* QKVb = (unsigned short*)alloc((size_t)1928 * 1536 * 2);
    unsigned short* attnb = (unsigned short*)alloc((size_t)65536 * 2);
    float* outsB = (float*)alloc((size_t)256 * 4);
    float* hpart = (float*)alloc((size_t)512 * 68 * 4);

    // 1: hist (first -> latency hidden) + pools + weight cvt
    k_prep<<<6912, 256, 0, stream>>>(features, patches, Wr, Wqkv, Wo, Wm,
                                     masks, probs,
                                     Gp, Xb, Wr_b, Wqkv_b, Wo_b, Wm_b, hpart);
    // 2: GEMM1 split-K=8 with fused gather (512 blocks)
    k_gemm128<true><<<dim3(4, 16, 8), 256, 0, stream>>>(
        Xb, Gp, Wr_b, Yp, 1928, 512, 4096, 512);
    // 3: reduce + br + LN1
    k_lnred<<<482, 256, 0, stream>>>(Yp, br, ln_g, ln_b, LNf, LNb, 1928, 8);
    // 4: QKV = LNb @ Wqkv^T + bqkv, bf16 out, 64x64 tiles (744 blocks)
    k_gemm64<<<dim3(24, 31), 256, 0, stream>>>(LNb, Wqkv_b, bqkv, QKVb, 1928, 1536, 512);
    // 5: attention (256 blocks)
    k_attn<<<dim3(8, 8, 4), 256, 0, stream>>>(QKVb, attnb);
    // 6: fused tail (Wo + LN + Wm + gelu + Wc), BK=64
    k_tail<<<8, 256, 0, stream>>>(attnb, Wo_b, bo, LNf, ln_g, ln_b,
                                  Wm_b, bm, Wc, bc, outsB);
    // 7: final gather (hist reduce + newv per block)
    k_out<<<2048, 256, 0, stream>>>(masks, probs, hpart, outsB, out);
}